// Round 1
// baseline (456.858 us; speedup 1.0000x reference)
//
#include <hip/hip_runtime.h>
#include <hip/hip_bf16.h>

typedef __attribute__((ext_vector_type(4))) float f32x4;
typedef __attribute__((ext_vector_type(8))) short s16x8;

#define MFMA_BF16(a, b, c) __builtin_amdgcn_mfma_f32_16x16x32_bf16(a, b, c, 0, 0, 0)

__device__ __forceinline__ short f2bf(float f) {
  unsigned u = __builtin_bit_cast(unsigned, f);
  u += 0x7fffu + ((u >> 16) & 1u);
  return (short)(u >> 16);
}

// ---------------------------------------------------------------------------
// GEMM tiles: 128x128, BK=32, 4 waves (2x2), each wave 64x64 = 4x4 frags.
// LDS rows padded to 40 bf16 (80 B) -> b128 accesses hit all 8 16B slots.
// ---------------------------------------------------------------------------
#define BM 128
#define BN 128
#define BK 32
#define LDA 40

// QKV = X @ W_qkv + b_qkv, scattered to qkv[3][24][4096][64] bf16
__global__ __launch_bounds__(256) void qkv_gemm(
    const float* __restrict__ X, const float* __restrict__ W,
    const float* __restrict__ bias, unsigned short* __restrict__ qkv) {
  __shared__ short As[BM * LDA];
  __shared__ short Bs[BN * LDA];
  const int K = 768, Nc = 2304;
  const int m0 = blockIdx.x * BM, n0 = blockIdx.y * BN;
  const int tid = threadIdx.x, lane = tid & 63, wid = tid >> 6;
  const int wr = wid >> 1, wc = wid & 1;
  const int lr = lane & 15, lk = (lane >> 4) * 8;
  const int sr = tid & 127, sc = (tid >> 7) * 16;

  f32x4 acc[4][4];
#pragma unroll
  for (int i = 0; i < 4; ++i)
#pragma unroll
    for (int j = 0; j < 4; ++j)
#pragma unroll
      for (int e = 0; e < 4; ++e) acc[i][j][e] = 0.f;

  for (int k0 = 0; k0 < K; k0 += BK) {
    {  // stage A (fp32 -> bf16), rows m0+sr, k chunk sc..sc+15
      const float* src = X + (size_t)(m0 + sr) * K + k0 + sc;
      s16x8 p0, p1;
#pragma unroll
      for (int i = 0; i < 4; ++i) {
        f32x4 f0 = *(const f32x4*)(src + i * 4);
#pragma unroll
        for (int e = 0; e < 4; ++e) {
          if (i < 2) p0[i * 4 + e] = f2bf(f0[e]);
          else       p1[(i - 2) * 4 + e] = f2bf(f0[e]);
        }
      }
      *(s16x8*)&As[sr * LDA + sc] = p0;
      *(s16x8*)&As[sr * LDA + sc + 8] = p1;
    }
    {  // stage B transposed: Bs[n][k], coalesced scalar reads of W
      const float* src = W + (size_t)(k0 + sc) * Nc + n0 + sr;
      s16x8 p0, p1;
#pragma unroll
      for (int i = 0; i < 8; ++i) p0[i] = f2bf(src[(size_t)i * Nc]);
#pragma unroll
      for (int i = 0; i < 8; ++i) p1[i] = f2bf(src[(size_t)(8 + i) * Nc]);
      *(s16x8*)&Bs[sr * LDA + sc] = p0;
      *(s16x8*)&Bs[sr * LDA + sc + 8] = p1;
    }
    __syncthreads();
    s16x8 af[4], bfr[4];
#pragma unroll
    for (int mi = 0; mi < 4; ++mi)
      af[mi] = *(const s16x8*)&As[(wr * 64 + mi * 16 + lr) * LDA + lk];
#pragma unroll
    for (int ni = 0; ni < 4; ++ni)
      bfr[ni] = *(const s16x8*)&Bs[(wc * 64 + ni * 16 + lr) * LDA + lk];
#pragma unroll
    for (int mi = 0; mi < 4; ++mi)
#pragma unroll
      for (int ni = 0; ni < 4; ++ni)
        acc[mi][ni] = MFMA_BF16(af[mi], bfr[ni], acc[mi][ni]);
    __syncthreads();
  }

  const int rbase = m0 + wr * 64 + (lane >> 4) * 4;
#pragma unroll
  for (int ni = 0; ni < 4; ++ni) {
    const int cb = n0 + wc * 64 + ni * 16;   // 16-aligned: which/h constant
    const int which = cb / 768;
    const int rem = cb - which * 768;
    const int h = rem >> 6;
    const int d = (rem & 63) + lr;
    const float bi = bias[cb + lr];
#pragma unroll
    for (int mi = 0; mi < 4; ++mi) {
#pragma unroll
      for (int j = 0; j < 4; ++j) {
        const int row = rbase + mi * 16 + j;
        const int bb = row >> 12, t = row & 4095;
        const float v = acc[mi][ni][j] + bi;
        qkv[((size_t)((which * 24 + bb * 12 + h) * 4096 + t)) * 64 + d] =
            (unsigned short)f2bf(v);
      }
    }
  }
}

// ---------------------------------------------------------------------------
// Flash attention: QBLK=128 (8 waves x 16 rows), KVBLK=64, D=64, bf16 MFMA.
// ---------------------------------------------------------------------------
#define LV 72

__global__ __launch_bounds__(512) void attn_fwd(
    const unsigned short* __restrict__ Qg, const unsigned short* __restrict__ Kg,
    const unsigned short* __restrict__ Vg, unsigned short* __restrict__ Aout) {
  __shared__ short Ks[64 * LV];
  __shared__ short Vt[64 * LV];      // transposed: Vt[d][key]
  __shared__ short Ps[8 * 16 * LV];  // per-wave P tile
  const int qt = blockIdx.x, bh = blockIdx.y;
  const unsigned short* Qh = Qg + (size_t)bh * 4096 * 64;
  const unsigned short* Kh = Kg + (size_t)bh * 4096 * 64;
  const unsigned short* Vh = Vg + (size_t)bh * 4096 * 64;
  const int tid = threadIdx.x, lane = tid & 63, wid = tid >> 6;
  const int lr = lane & 15, lk = (lane >> 4) * 8;
  const int q0 = qt * 128 + wid * 16;

  s16x8 qf[2];
  qf[0] = *(const s16x8*)&Qh[(size_t)(q0 + lr) * 64 + lk];
  qf[1] = *(const s16x8*)&Qh[(size_t)(q0 + lr) * 64 + 32 + lk];

  f32x4 o[4];
  float mrow[4], lsum[4];
#pragma unroll
  for (int i = 0; i < 4; ++i) {
#pragma unroll
    for (int e = 0; e < 4; ++e) o[i][e] = 0.f;
    mrow[i] = -1e30f;
    lsum[i] = 0.f;
  }

  const int ksr = tid >> 3, ksc = (tid & 7) * 8;  // K staging: 16B per thread
  const int vd = tid & 63, vk0 = (tid >> 6) * 8;  // V staging: transpose

  short* Pw = &Ps[wid * 16 * LV];

  for (int kv0 = 0; kv0 < 4096; kv0 += 64) {
    *(s16x8*)&Ks[ksr * LV + ksc] =
        *(const s16x8*)&Kh[(size_t)(kv0 + ksr) * 64 + ksc];
    {
      s16x8 vv;
#pragma unroll
      for (int i = 0; i < 8; ++i)
        vv[i] = (short)Vh[(size_t)(kv0 + vk0 + i) * 64 + vd];
      *(s16x8*)&Vt[vd * LV + vk0] = vv;
    }
    __syncthreads();

    // S = Q K^T  (per wave: 16 rows x 64 keys)
    f32x4 s[4];
#pragma unroll
    for (int kf = 0; kf < 4; ++kf) {
      s16x8 k0f = *(const s16x8*)&Ks[(kf * 16 + lr) * LV + lk];
      s16x8 k1f = *(const s16x8*)&Ks[(kf * 16 + lr) * LV + 32 + lk];
      f32x4 t;
#pragma unroll
      for (int e = 0; e < 4; ++e) t[e] = 0.f;
      t = MFMA_BF16(qf[0], k0f, t);
      t = MFMA_BF16(qf[1], k1f, t);
      s[kf] = t;
    }

    // online softmax (rows live on 16-lane groups)
    float pv[4][4], scl[4];
#pragma unroll
    for (int j = 0; j < 4; ++j) {
      float mx = fmaxf(fmaxf(s[0][j], s[1][j]), fmaxf(s[2][j], s[3][j])) * 0.125f;
#pragma unroll
      for (int d = 1; d < 16; d <<= 1) mx = fmaxf(mx, __shfl_xor(mx, d));
      const float mnew = fmaxf(mrow[j], mx);
      float sum = 0.f;
#pragma unroll
      for (int kf = 0; kf < 4; ++kf) {
        const float p = __expf(s[kf][j] * 0.125f - mnew);
        pv[kf][j] = p;
        sum += p;
      }
#pragma unroll
      for (int d = 1; d < 16; d <<= 1) sum += __shfl_xor(sum, d);
      scl[j] = __expf(mrow[j] - mnew);
      lsum[j] = lsum[j] * scl[j] + sum;
      mrow[j] = mnew;
    }
#pragma unroll
    for (int df = 0; df < 4; ++df)
#pragma unroll
      for (int j = 0; j < 4; ++j) o[df][j] *= scl[j];

    // P (C-layout) -> LDS -> A-layout frags
#pragma unroll
    for (int j = 0; j < 4; ++j)
#pragma unroll
      for (int kf = 0; kf < 4; ++kf)
        Pw[((lane >> 4) * 4 + j) * LV + kf * 16 + lr] = f2bf(pv[kf][j]);
    __syncthreads();

    // O += P V
#pragma unroll
    for (int ks = 0; ks < 2; ++ks) {
      s16x8 pf = *(const s16x8*)&Pw[lr * LV + ks * 32 + lk];
#pragma unroll
      for (int df = 0; df < 4; ++df) {
        s16x8 vf = *(const s16x8*)&Vt[(df * 16 + lr) * LV + ks * 32 + lk];
        o[df] = MFMA_BF16(pf, vf, o[df]);
      }
    }
    __syncthreads();
  }

  const int b = bh / 12, h = bh - b * 12;
#pragma unroll
  for (int df = 0; df < 4; ++df)
#pragma unroll
    for (int j = 0; j < 4; ++j) {
      const int tok = q0 + (lane >> 4) * 4 + j;
      const float v = o[df][j] / lsum[j];
      Aout[((size_t)(b * 4096 + tok)) * 768 + h * 64 + df * 16 + lr] =
          (unsigned short)f2bf(v);
    }
}

// ---------------------------------------------------------------------------
// out = attn @ W_proj + b_proj  (A bf16, W fp32->bf16, out fp32)
// ---------------------------------------------------------------------------
__global__ __launch_bounds__(256) void proj_gemm(
    const unsigned short* __restrict__ A, const float* __restrict__ W,
    const float* __restrict__ bias, float* __restrict__ out) {
  __shared__ short As[BM * LDA];
  __shared__ short Bs[BN * LDA];
  const int K = 768, Nc = 768;
  const int m0 = blockIdx.x * BM, n0 = blockIdx.y * BN;
  const int tid = threadIdx.x, lane = tid & 63, wid = tid >> 6;
  const int wr = wid >> 1, wc = wid & 1;
  const int lr = lane & 15, lk = (lane >> 4) * 8;
  const int sr = tid & 127, sc = (tid >> 7) * 16;

  f32x4 acc[4][4];
#pragma unroll
  for (int i = 0; i < 4; ++i)
#pragma unroll
    for (int j = 0; j < 4; ++j)
#pragma unroll
      for (int e = 0; e < 4; ++e) acc[i][j][e] = 0.f;

  for (int k0 = 0; k0 < K; k0 += BK) {
    {
      const unsigned short* src = A + (size_t)(m0 + sr) * K + k0 + sc;
      *(s16x8*)&As[sr * LDA + sc] = *(const s16x8*)src;
      *(s16x8*)&As[sr * LDA + sc + 8] = *(const s16x8*)(src + 8);
    }
    {
      const float* src = W + (size_t)(k0 + sc) * Nc + n0 + sr;
      s16x8 p0, p1;
#pragma unroll
      for (int i = 0; i < 8; ++i) p0[i] = f2bf(src[(size_t)i * Nc]);
#pragma unroll
      for (int i = 0; i < 8; ++i) p1[i] = f2bf(src[(size_t)(8 + i) * Nc]);
      *(s16x8*)&Bs[sr * LDA + sc] = p0;
      *(s16x8*)&Bs[sr * LDA + sc + 8] = p1;
    }
    __syncthreads();
    s16x8 af[4], bfr[4];
#pragma unroll
    for (int mi = 0; mi < 4; ++mi)
      af[mi] = *(const s16x8*)&As[(wr * 64 + mi * 16 + lr) * LDA + lk];
#pragma unroll
    for (int ni = 0; ni < 4; ++ni)
      bfr[ni] = *(const s16x8*)&Bs[(wc * 64 + ni * 16 + lr) * LDA + lk];
#pragma unroll
    for (int mi = 0; mi < 4; ++mi)
#pragma unroll
      for (int ni = 0; ni < 4; ++ni)
        acc[mi][ni] = MFMA_BF16(af[mi], bfr[ni], acc[mi][ni]);
    __syncthreads();
  }

  const int rbase = m0 + wr * 64 + (lane >> 4) * 4;
#pragma unroll
  for (int ni = 0; ni < 4; ++ni) {
    const int cb = n0 + wc * 64 + ni * 16;
    const float bi = bias[cb + lr];
#pragma unroll
    for (int mi = 0; mi < 4; ++mi) {
#pragma unroll
      for (int j = 0; j < 4; ++j) {
        const int row = rbase + mi * 16 + j;
        out[(size_t)row * 768 + cb + lr] = acc[mi][ni][j] + bi;
      }
    }
  }
}

extern "C" void kernel_launch(void* const* d_in, const int* in_sizes, int n_in,
                              void* d_out, int out_size, void* d_ws, size_t ws_size,
                              hipStream_t stream) {
  const float* x = (const float*)d_in[0];
  const float* W_qkv = (const float*)d_in[1];
  const float* b_qkv = (const float*)d_in[2];
  const float* W_proj = (const float*)d_in[3];
  const float* b_proj = (const float*)d_in[4];
  float* out = (float*)d_out;

  unsigned short* qkv = (unsigned short*)d_ws;  // [3][24][4096][64] bf16
  const size_t NQ = (size_t)24 * 4096 * 64;
  unsigned short* attn = qkv + 3 * NQ;          // [8192][768] bf16

  qkv_gemm<<<dim3(64, 18), 256, 0, stream>>>(x, W_qkv, b_qkv, qkv);
  attn_fwd<<<dim3(32, 24), 512, 0, stream>>>(qkv, qkv + NQ, qkv + 2 * NQ, attn);
  proj_gemm<<<dim3(64, 6), 256, 0, stream>>>(attn, W_proj, b_proj, out);
}

// Round 2
// 427.933 us; speedup vs baseline: 1.0676x; 1.0676x over previous
//
#include <hip/hip_runtime.h>
#include <hip/hip_bf16.h>

typedef __attribute__((ext_vector_type(4))) float f32x4;
typedef __attribute__((ext_vector_type(8))) short s16x8;

#define MFMA_BF16(a, b, c) __builtin_amdgcn_mfma_f32_16x16x32_bf16(a, b, c, 0, 0, 0)

__device__ __forceinline__ short f2bf(float f) {
  unsigned u = __builtin_bit_cast(unsigned, f);
  u += 0x7fffu + ((u >> 16) & 1u);
  return (short)(u >> 16);
}

// ---------------------------------------------------------------------------
// GEMM tiles: 128x128, BK=32, 4 waves (2x2), each wave 64x64 = 4x4 frags.
// ---------------------------------------------------------------------------
#define BM 128
#define BN 128
#define BK 32
#define LDA 40

// QKV = X @ W_qkv + b_qkv. Q scaled by SCALE*log2e, stored [bh][tok][d];
// K stored [bh][tok][d]; V stored TRANSPOSED [bh][d][tok].
__global__ __launch_bounds__(256) void qkv_gemm(
    const float* __restrict__ X, const float* __restrict__ W,
    const float* __restrict__ bias, unsigned short* __restrict__ Qo,
    unsigned short* __restrict__ Ko, unsigned short* __restrict__ VTo) {
  __shared__ short As[BM * LDA];
  __shared__ short Bs[BN * LDA];
  const int K = 768, Nc = 2304;
  const int m0 = blockIdx.x * BM, n0 = blockIdx.y * BN;
  const int tid = threadIdx.x, lane = tid & 63, wid = tid >> 6;
  const int wr = wid >> 1, wc = wid & 1;
  const int lr = lane & 15, lk = (lane >> 4) * 8;
  const int sr = tid & 127, sc = (tid >> 7) * 16;

  f32x4 acc[4][4];
#pragma unroll
  for (int i = 0; i < 4; ++i)
#pragma unroll
    for (int j = 0; j < 4; ++j)
#pragma unroll
      for (int e = 0; e < 4; ++e) acc[i][j][e] = 0.f;

  for (int k0 = 0; k0 < K; k0 += BK) {
    {  // stage A (fp32 -> bf16)
      const float* src = X + (size_t)(m0 + sr) * K + k0 + sc;
      s16x8 p0, p1;
#pragma unroll
      for (int i = 0; i < 4; ++i) {
        f32x4 f0 = *(const f32x4*)(src + i * 4);
#pragma unroll
        for (int e = 0; e < 4; ++e) {
          if (i < 2) p0[i * 4 + e] = f2bf(f0[e]);
          else       p1[(i - 2) * 4 + e] = f2bf(f0[e]);
        }
      }
      *(s16x8*)&As[sr * LDA + sc] = p0;
      *(s16x8*)&As[sr * LDA + sc + 8] = p1;
    }
    {  // stage B transposed: Bs[n][k]
      const float* src = W + (size_t)(k0 + sc) * Nc + n0 + sr;
      s16x8 p0, p1;
#pragma unroll
      for (int i = 0; i < 8; ++i) p0[i] = f2bf(src[(size_t)i * Nc]);
#pragma unroll
      for (int i = 0; i < 8; ++i) p1[i] = f2bf(src[(size_t)(8 + i) * Nc]);
      *(s16x8*)&Bs[sr * LDA + sc] = p0;
      *(s16x8*)&Bs[sr * LDA + sc + 8] = p1;
    }
    __syncthreads();
    s16x8 af[4], bfr[4];
#pragma unroll
    for (int mi = 0; mi < 4; ++mi)
      af[mi] = *(const s16x8*)&As[(wr * 64 + mi * 16 + lr) * LDA + lk];
#pragma unroll
    for (int ni = 0; ni < 4; ++ni)
      bfr[ni] = *(const s16x8*)&Bs[(wc * 64 + ni * 16 + lr) * LDA + lk];
#pragma unroll
    for (int mi = 0; mi < 4; ++mi)
#pragma unroll
      for (int ni = 0; ni < 4; ++ni)
        acc[mi][ni] = MFMA_BF16(af[mi], bfr[ni], acc[mi][ni]);
    __syncthreads();
  }

  const float QSC = 0.18033688011f;  // 0.125 * log2(e)
  const int rbase = m0 + wr * 64 + (lane >> 4) * 4;
#pragma unroll
  for (int ni = 0; ni < 4; ++ni) {
    const int cb = n0 + wc * 64 + ni * 16;  // 16-aligned: which/h uniform
    const int which = cb / 768;
    const int rem = cb - which * 768;
    const int h = rem >> 6;
    const int d = (rem & 63) + lr;
    const float bi = bias[cb + lr];
#pragma unroll
    for (int mi = 0; mi < 4; ++mi) {
#pragma unroll
      for (int j = 0; j < 4; ++j) {
        const int row = rbase + mi * 16 + j;
        const int bb = row >> 12, t = row & 4095;
        const float v = acc[mi][ni][j] + bi;
        const size_t hb = (size_t)(bb * 12 + h);
        if (which == 0)
          Qo[(hb * 4096 + t) * 64 + d] = (unsigned short)f2bf(v * QSC);
        else if (which == 1)
          Ko[(hb * 4096 + t) * 64 + d] = (unsigned short)f2bf(v);
        else
          VTo[(hb * 64 + d) * 4096 + t] = (unsigned short)f2bf(v);
      }
    }
  }
}

// ---------------------------------------------------------------------------
// Flash attention: QBLK=128 (8 waves x 16 q), KVBLK=64, D=64.
// XOR-swizzled LDS (byte ^= (row&7)<<4), reg-staged double buffer, 1 barrier/it.
// Element [r][c] lives at short index r*64 + (((c>>3) ^ (r&7))<<3) + (c&7).
// ---------------------------------------------------------------------------
__global__ __launch_bounds__(512) void attn_fwd(
    const unsigned short* __restrict__ Qg, const unsigned short* __restrict__ Kg,
    const unsigned short* __restrict__ VTg, unsigned short* __restrict__ Aout) {
  __shared__ short Ks[2][64 * 64];
  __shared__ short Vs[2][64 * 64];
  __shared__ short Ps[8][16 * 64];
  const int qt = blockIdx.x, bh = blockIdx.y;
  const unsigned short* Qh = Qg + (size_t)bh * 4096 * 64;
  const unsigned short* Kh = Kg + (size_t)bh * 4096 * 64;
  const unsigned short* Vh = VTg + (size_t)bh * 4096 * 64;  // [d][tok]
  const int tid = threadIdx.x, lane = tid & 63, wid = tid >> 6;
  const int lr = lane & 15, g = lane >> 4, lr7 = lr & 7;
  const int q0 = qt * 128 + wid * 16;

  s16x8 qf0 = *(const s16x8*)&Qh[(size_t)(q0 + lr) * 64 + g * 8];
  s16x8 qf1 = *(const s16x8*)&Qh[(size_t)(q0 + lr) * 64 + 32 + g * 8];

  // staging: 512 threads cover one 64x64 tile (16B each), swizzled dest
  const int srow = tid >> 3, sslot = tid & 7;
  const int sdst = srow * 64 + (((sslot ^ (srow & 7))) << 3);
  const unsigned short* kga = Kh + (size_t)srow * 64 + sslot * 8;
  const unsigned short* vga = Vh + (size_t)srow * 4096 + sslot * 8;

  f32x4 o[4];
  float mrow[4], lsum[4];
#pragma unroll
  for (int i = 0; i < 4; ++i) {
#pragma unroll
    for (int e = 0; e < 4; ++e) o[i][e] = 0.f;
    mrow[i] = -1e30f;
    lsum[i] = 0.f;
  }

  short* Pw = Ps[wid];

  // prologue: stage tile 0
  s16x8 kreg = *(const s16x8*)kga;
  s16x8 vreg = *(const s16x8*)vga;
  *(s16x8*)&Ks[0][sdst] = kreg;
  *(s16x8*)&Vs[0][sdst] = vreg;
  __syncthreads();

  int cur = 0;
  for (int t = 0; t < 64; ++t) {
    if (t < 63) {  // issue next-tile loads early; write after compute
      kreg = *(const s16x8*)(kga + (size_t)(t + 1) * 4096);
      vreg = *(const s16x8*)(vga + (t + 1) * 64);
    }

    // S = Q K^T (16 q x 64 keys per wave)
    f32x4 s[4];
    const short* Kc = Ks[cur];
    __builtin_amdgcn_s_setprio(1);
#pragma unroll
    for (int kf = 0; kf < 4; ++kf) {
      const int row = kf * 16 + lr;
      s16x8 k0f = *(const s16x8*)&Kc[row * 64 + ((g ^ lr7) << 3)];
      s16x8 k1f = *(const s16x8*)&Kc[row * 64 + (((4 + g) ^ lr7) << 3)];
      f32x4 tt;
#pragma unroll
      for (int e = 0; e < 4; ++e) tt[e] = 0.f;
      tt = MFMA_BF16(qf0, k0f, tt);
      tt = MFMA_BF16(qf1, k1f, tt);
      s[kf] = tt;
    }
    __builtin_amdgcn_s_setprio(0);

    // online softmax in exp2 domain (scale pre-folded into Q)
    float pv[4][4], scl[4];
#pragma unroll
    for (int j = 0; j < 4; ++j) {
      float mx = fmaxf(fmaxf(s[0][j], s[1][j]), fmaxf(s[2][j], s[3][j]));
#pragma unroll
      for (int d = 1; d < 16; d <<= 1) mx = fmaxf(mx, __shfl_xor(mx, d));
      const float mnew = fmaxf(mrow[j], mx);
      float sum = 0.f;
#pragma unroll
      for (int kf = 0; kf < 4; ++kf) {
        const float p = exp2f(s[kf][j] - mnew);
        pv[kf][j] = p;
        sum += p;
      }
#pragma unroll
      for (int d = 1; d < 16; d <<= 1) sum += __shfl_xor(sum, d);
      scl[j] = exp2f(mrow[j] - mnew);
      lsum[j] = lsum[j] * scl[j] + sum;
      mrow[j] = mnew;
    }
#pragma unroll
    for (int df = 0; df < 4; ++df)
#pragma unroll
      for (int j = 0; j < 4; ++j) o[df][j] *= scl[j];

    // P (C-layout) -> per-wave LDS (swizzled), no cross-wave barrier needed
#pragma unroll
    for (int j = 0; j < 4; ++j) {
      const int rp = g * 4 + j;
#pragma unroll
      for (int kf = 0; kf < 4; ++kf)
        Pw[rp * 64 + (((kf * 2 + (lr >> 3)) ^ (rp & 7)) << 3) + (lr & 7)] =
            f2bf(pv[kf][j]);
    }

    // O += P V
    const short* Vc = Vs[cur];
    __builtin_amdgcn_s_setprio(1);
#pragma unroll
    for (int ks = 0; ks < 2; ++ks) {
      s16x8 pf = *(const s16x8*)&Pw[lr * 64 + (((ks * 4 + g) ^ lr7) << 3)];
#pragma unroll
      for (int df = 0; df < 4; ++df) {
        const int row = df * 16 + lr;
        s16x8 vf = *(const s16x8*)&Vc[row * 64 + (((ks * 4 + g) ^ lr7) << 3)];
        o[df] = MFMA_BF16(pf, vf, o[df]);
      }
    }
    __builtin_amdgcn_s_setprio(0);

    if (t < 63) {  // write prefetched tile into the other buffer
      *(s16x8*)&Ks[cur ^ 1][sdst] = kreg;
      *(s16x8*)&Vs[cur ^ 1][sdst] = vreg;
      __syncthreads();
      cur ^= 1;
    }
  }

  const int b = bh / 12, h = bh - b * 12;
  float inv[4];
#pragma unroll
  for (int j = 0; j < 4; ++j) inv[j] = 1.0f / lsum[j];
#pragma unroll
  for (int df = 0; df < 4; ++df)
#pragma unroll
    for (int j = 0; j < 4; ++j) {
      const int tok = q0 + g * 4 + j;
      Aout[((size_t)(b * 4096 + tok)) * 768 + h * 64 + df * 16 + lr] =
          (unsigned short)f2bf(o[df][j] * inv[j]);
    }
}

// ---------------------------------------------------------------------------
// out = attn @ W_proj + b_proj  (A bf16, W fp32->bf16, out fp32)
// ---------------------------------------------------------------------------
__global__ __launch_bounds__(256) void proj_gemm(
    const unsigned short* __restrict__ A, const float* __restrict__ W,
    const float* __restrict__ bias, float* __restrict__ out) {
  __shared__ short As[BM * LDA];
  __shared__ short Bs[BN * LDA];
  const int K = 768, Nc = 768;
  const int m0 = blockIdx.x * BM, n0 = blockIdx.y * BN;
  const int tid = threadIdx.x, lane = tid & 63, wid = tid >> 6;
  const int wr = wid >> 1, wc = wid & 1;
  const int lr = lane & 15, lk = (lane >> 4) * 8;
  const int sr = tid & 127, sc = (tid >> 7) * 16;

  f32x4 acc[4][4];
#pragma unroll
  for (int i = 0; i < 4; ++i)
#pragma unroll
    for (int j = 0; j < 4; ++j)
#pragma unroll
      for (int e = 0; e < 4; ++e) acc[i][j][e] = 0.f;

  for (int k0 = 0; k0 < K; k0 += BK) {
    {
      const unsigned short* src = A + (size_t)(m0 + sr) * K + k0 + sc;
      *(s16x8*)&As[sr * LDA + sc] = *(const s16x8*)src;
      *(s16x8*)&As[sr * LDA + sc + 8] = *(const s16x8*)(src + 8);
    }
    {
      const float* src = W + (size_t)(k0 + sc) * Nc + n0 + sr;
      s16x8 p0, p1;
#pragma unroll
      for (int i = 0; i < 8; ++i) p0[i] = f2bf(src[(size_t)i * Nc]);
#pragma unroll
      for (int i = 0; i < 8; ++i) p1[i] = f2bf(src[(size_t)(8 + i) * Nc]);
      *(s16x8*)&Bs[sr * LDA + sc] = p0;
      *(s16x8*)&Bs[sr * LDA + sc + 8] = p1;
    }
    __syncthreads();
    s16x8 af[4], bfr[4];
#pragma unroll
    for (int mi = 0; mi < 4; ++mi)
      af[mi] = *(const s16x8*)&As[(wr * 64 + mi * 16 + lr) * LDA + lk];
#pragma unroll
    for (int ni = 0; ni < 4; ++ni)
      bfr[ni] = *(const s16x8*)&Bs[(wc * 64 + ni * 16 + lr) * LDA + lk];
#pragma unroll
    for (int mi = 0; mi < 4; ++mi)
#pragma unroll
      for (int ni = 0; ni < 4; ++ni)
        acc[mi][ni] = MFMA_BF16(af[mi], bfr[ni], acc[mi][ni]);
    __syncthreads();
  }

  const int rbase = m0 + wr * 64 + (lane >> 4) * 4;
#pragma unroll
  for (int ni = 0; ni < 4; ++ni) {
    const int cb = n0 + wc * 64 + ni * 16;
    const float bi = bias[cb + lr];
#pragma unroll
    for (int mi = 0; mi < 4; ++mi) {
#pragma unroll
      for (int j = 0; j < 4; ++j) {
        const int row = rbase + mi * 16 + j;
        out[(size_t)row * 768 + cb + lr] = acc[mi][ni][j] + bi;
      }
    }
  }
}

extern "C" void kernel_launch(void* const* d_in, const int* in_sizes, int n_in,
                              void* d_out, int out_size, void* d_ws, size_t ws_size,
                              hipStream_t stream) {
  const float* x = (const float*)d_in[0];
  const float* W_qkv = (const float*)d_in[1];
  const float* b_qkv = (const float*)d_in[2];
  const float* W_proj = (const float*)d_in[3];
  const float* b_proj = (const float*)d_in[4];
  float* out = (float*)d_out;

  unsigned short* ws = (unsigned short*)d_ws;
  const size_t NQ = (size_t)24 * 4096 * 64;
  unsigned short* q = ws;            // [24][4096][64]
  unsigned short* k = ws + NQ;       // [24][4096][64]
  unsigned short* vt = ws + 2 * NQ;  // [24][64][4096]
  unsigned short* attn = ws + 3 * NQ;

  qkv_gemm<<<dim3(64, 18), 256, 0, stream>>>(x, W_qkv, b_qkv, q, k, vt);
  attn_fwd<<<dim3(32, 24), 512, 0, stream>>>(q, k, vt, attn);
  proj_gemm<<<dim3(64, 6), 256, 0, stream>>>(attn, W_proj, b_proj, out);
}

// Round 3
// 369.115 us; speedup vs baseline: 1.2377x; 1.1593x over previous
//
#include <hip/hip_runtime.h>
#include <hip/hip_bf16.h>

typedef __attribute__((ext_vector_type(4))) float f32x4;
typedef __attribute__((ext_vector_type(16))) float f32x16;
typedef __attribute__((ext_vector_type(8))) short s16x8;
typedef __attribute__((ext_vector_type(4))) unsigned int u32x4;

#define MFMA16(a, b, c) __builtin_amdgcn_mfma_f32_16x16x32_bf16(a, b, c, 0, 0, 0)
#define MFMA32(a, b, c) __builtin_amdgcn_mfma_f32_32x32x16_bf16(a, b, c, 0, 0, 0)

__device__ __forceinline__ short f2bf(float f) {
  unsigned u = __builtin_bit_cast(unsigned, f);
  u += 0x7fffu + ((u >> 16) & 1u);
  return (short)(u >> 16);
}
__device__ __forceinline__ unsigned pk2(float x, float y) {
  return (unsigned)(unsigned short)f2bf(x) | ((unsigned)(unsigned short)f2bf(y) << 16);
}

// ---------------------------------------------------------------------------
// GEMM tiles: 128x128, BK=32, 4 waves (2x2), each wave 64x64 = 4x4 frags.
// ---------------------------------------------------------------------------
#define BM 128
#define BN 128
#define BK 32
#define LDA 40

__global__ __launch_bounds__(256) void qkv_gemm(
    const float* __restrict__ X, const float* __restrict__ W,
    const float* __restrict__ bias, unsigned short* __restrict__ Qo,
    unsigned short* __restrict__ Ko, unsigned short* __restrict__ VTo) {
  __shared__ short As[BM * LDA];
  __shared__ short Bs[BN * LDA];
  const int K = 768, Nc = 2304;
  const int m0 = blockIdx.x * BM, n0 = blockIdx.y * BN;
  const int tid = threadIdx.x, lane = tid & 63, wid = tid >> 6;
  const int wr = wid >> 1, wc = wid & 1;
  const int lr = lane & 15, lk = (lane >> 4) * 8;
  const int sr = tid & 127, sc = (tid >> 7) * 16;

  f32x4 acc[4][4];
#pragma unroll
  for (int i = 0; i < 4; ++i)
#pragma unroll
    for (int j = 0; j < 4; ++j)
#pragma unroll
      for (int e = 0; e < 4; ++e) acc[i][j][e] = 0.f;

  for (int k0 = 0; k0 < K; k0 += BK) {
    {
      const float* src = X + (size_t)(m0 + sr) * K + k0 + sc;
      s16x8 p0, p1;
#pragma unroll
      for (int i = 0; i < 4; ++i) {
        f32x4 f0 = *(const f32x4*)(src + i * 4);
#pragma unroll
        for (int e = 0; e < 4; ++e) {
          if (i < 2) p0[i * 4 + e] = f2bf(f0[e]);
          else       p1[(i - 2) * 4 + e] = f2bf(f0[e]);
        }
      }
      *(s16x8*)&As[sr * LDA + sc] = p0;
      *(s16x8*)&As[sr * LDA + sc + 8] = p1;
    }
    {
      const float* src = W + (size_t)(k0 + sc) * Nc + n0 + sr;
      s16x8 p0, p1;
#pragma unroll
      for (int i = 0; i < 8; ++i) p0[i] = f2bf(src[(size_t)i * Nc]);
#pragma unroll
      for (int i = 0; i < 8; ++i) p1[i] = f2bf(src[(size_t)(8 + i) * Nc]);
      *(s16x8*)&Bs[sr * LDA + sc] = p0;
      *(s16x8*)&Bs[sr * LDA + sc + 8] = p1;
    }
    __syncthreads();
    s16x8 af[4], bfr[4];
#pragma unroll
    for (int mi = 0; mi < 4; ++mi)
      af[mi] = *(const s16x8*)&As[(wr * 64 + mi * 16 + lr) * LDA + lk];
#pragma unroll
    for (int ni = 0; ni < 4; ++ni)
      bfr[ni] = *(const s16x8*)&Bs[(wc * 64 + ni * 16 + lr) * LDA + lk];
#pragma unroll
    for (int mi = 0; mi < 4; ++mi)
#pragma unroll
      for (int ni = 0; ni < 4; ++ni)
        acc[mi][ni] = MFMA16(af[mi], bfr[ni], acc[mi][ni]);
    __syncthreads();
  }

  const float QSC = 0.18033688011f;  // 0.125 * log2(e)
  const int rbase = m0 + wr * 64 + (lane >> 4) * 4;
#pragma unroll
  for (int ni = 0; ni < 4; ++ni) {
    const int cb = n0 + wc * 64 + ni * 16;
    const int which = cb / 768;
    const int rem = cb - which * 768;
    const int h = rem >> 6;
    const int d = (rem & 63) + lr;
    const float bi = bias[cb + lr];
#pragma unroll
    for (int mi = 0; mi < 4; ++mi) {
#pragma unroll
      for (int j = 0; j < 4; ++j) {
        const int row = rbase + mi * 16 + j;
        const int bb = row >> 12, t = row & 4095;
        const float v = acc[mi][ni][j] + bi;
        const size_t hb = (size_t)(bb * 12 + h);
        if (which == 0)
          Qo[(hb * 4096 + t) * 64 + d] = (unsigned short)f2bf(v * QSC);
        else if (which == 1)
          Ko[(hb * 4096 + t) * 64 + d] = (unsigned short)f2bf(v);
        else
          VTo[(hb * 64 + d) * 4096 + t] = (unsigned short)f2bf(v);
      }
    }
  }
}

// ---------------------------------------------------------------------------
// Flash attention, swapped-QK^T 32x32 structure:
// 4 warps x 32 q-rows, KVBLK=64, mfma_f32_32x32x16_bf16.
// S^T = mfma(K,Q): lane holds 32 of 64 keys of P-row q=lane&31 (other half on
// lane^32). Softmax lane-local + 1 swap. P packed in-register -> PV B-frag.
// O^T = mfma(VT, P): col=q stays lane-local for rescale.
// LDS: K/V double-buffered 64x64 tiles, XOR-swizzled (16B slot ^= row&7).
// ---------------------------------------------------------------------------
__global__ __launch_bounds__(256) void attn_fwd(
    const unsigned short* __restrict__ Qg, const unsigned short* __restrict__ Kg,
    const unsigned short* __restrict__ VTg, unsigned short* __restrict__ Aout) {
  __shared__ __align__(16) short smem[16384];  // [K0|K1|V0|V1] 4096 each
  const int qt = blockIdx.x, bh = blockIdx.y;
  const unsigned short* Qh = Qg + (size_t)bh * 4096 * 64;
  const unsigned short* Kh = Kg + (size_t)bh * 4096 * 64;
  const unsigned short* Vh = VTg + (size_t)bh * 4096 * 64;  // [d][tok]
  const int tid = threadIdx.x, lane = tid & 63, wid = tid >> 6;
  const int l31 = lane & 31, hi = lane >> 5, rs = l31 & 7;
  const int qbase = qt * 128 + wid * 32;

  // Q as B-fragments: row=q=l31, k = db*16 + hi*8 + i
  s16x8 qf[4];
#pragma unroll
  for (int db = 0; db < 4; ++db)
    qf[db] = *(const s16x8*)&Qh[(size_t)(qbase + l31) * 64 + db * 16 + hi * 8];

  f32x16 zf;
#pragma unroll
  for (int r = 0; r < 16; ++r) zf[r] = 0.f;
  f32x16 o0 = zf, o1 = zf;  // O^T: col=q=l31, regs=d (db2*32 + regmap)
  float m = -1e30f, l = 0.f;

  // staging: 256 threads x 32B per tile per matrix
  const int srow = tid >> 2, sp = tid & 3;
  const int sd0 = srow * 64 + (((sp * 2) ^ (srow & 7)) << 3);
  const int sd1 = srow * 64 + (((sp * 2 + 1) ^ (srow & 7)) << 3);
  const unsigned short* kga = Kh + srow * 64 + sp * 16;
  const unsigned short* vga = Vh + (size_t)srow * 4096 + sp * 16;

  s16x8 kr0 = *(const s16x8*)kga;
  s16x8 kr1 = *(const s16x8*)(kga + 8);
  s16x8 vr0 = *(const s16x8*)vga;
  s16x8 vr1 = *(const s16x8*)(vga + 8);
  *(s16x8*)&smem[sd0] = kr0;
  *(s16x8*)&smem[sd1] = kr1;
  *(s16x8*)&smem[8192 + sd0] = vr0;
  *(s16x8*)&smem[8192 + sd1] = vr1;
  __syncthreads();

  int cur = 0;
  for (int t = 0; t < 64; ++t) {
    if (t < 63) {
      kr0 = *(const s16x8*)(kga + (size_t)(t + 1) * 4096);
      kr1 = *(const s16x8*)(kga + (size_t)(t + 1) * 4096 + 8);
      vr0 = *(const s16x8*)(vga + (t + 1) * 64);
      vr1 = *(const s16x8*)(vga + (t + 1) * 64 + 8);
    }
    const short* Kc = smem + cur * 4096;
    const short* Vc = smem + 8192 + cur * 4096;

    // S^T = K . Q^T : per key-block kb, C[key][q] (col=q=l31)
    f32x16 sA = zf, sB = zf;
    __builtin_amdgcn_s_setprio(1);
#pragma unroll
    for (int db = 0; db < 4; ++db) {
      s16x8 kf = *(const s16x8*)&Kc[l31 * 64 + (((db * 2 + hi) ^ rs) << 3)];
      sA = MFMA32(kf, qf[db], sA);
    }
#pragma unroll
    for (int db = 0; db < 4; ++db) {
      s16x8 kf = *(const s16x8*)&Kc[(32 + l31) * 64 + (((db * 2 + hi) ^ rs) << 3)];
      sB = MFMA32(kf, qf[db], sB);
    }
    __builtin_amdgcn_s_setprio(0);

    // lane-local softmax for q=l31 (keys: 32 local + 32 on lane^32)
    float mx[16];
#pragma unroll
    for (int r = 0; r < 16; ++r) mx[r] = fmaxf(sA[r], sB[r]);
#pragma unroll
    for (int off = 8; off; off >>= 1)
#pragma unroll
      for (int r = 0; r < off; ++r) mx[r] = fmaxf(mx[r], mx[r + off]);
    const float pmax = fmaxf(mx[0], __shfl_xor(mx[0], 32));

    if (!__all(pmax <= m + 8.0f)) {  // defer-max (T13)
      const float mnew = fmaxf(m, pmax);
      const float scl = exp2f(m - mnew);
#pragma unroll
      for (int r = 0; r < 16; ++r) { o0[r] *= scl; o1[r] *= scl; }
      l *= scl;
      m = mnew;
    }
#pragma unroll
    for (int r = 0; r < 16; ++r) {
      sA[r] = exp2f(sA[r] - m);
      sB[r] = exp2f(sB[r] - m);
    }
    float t8[8];
#pragma unroll
    for (int r = 0; r < 8; ++r)
      t8[r] = (sA[r] + sA[r + 8]) + (sB[r] + sB[r + 8]);
#pragma unroll
    for (int off = 4; off; off >>= 1)
#pragma unroll
      for (int r = 0; r < off; ++r) t8[r] += t8[r + off];
    l += t8[0] + __shfl_xor(t8[0], 32);

    // Build PV B-fragments in-register: pf[kc] = P[q=l31][kc*16+hi*8+0..7]
    s16x8 pf0, pf1, pf2, pf3;
#define MAKE_PF(pfv, sv, base)                                          \
  {                                                                     \
    unsigned wa = pk2(sv[base + 0], sv[base + 1]);                      \
    unsigned wb = pk2(sv[base + 2], sv[base + 3]);                      \
    unsigned wc_ = pk2(sv[base + 4], sv[base + 5]);                     \
    unsigned wd = pk2(sv[base + 6], sv[base + 7]);                      \
    unsigned z0 = (unsigned)__shfl_xor((int)(hi ? wa : wc_), 32);       \
    unsigned z1 = (unsigned)__shfl_xor((int)(hi ? wb : wd), 32);        \
    u32x4 fw;                                                           \
    fw[0] = hi ? z0 : wa;                                               \
    fw[1] = hi ? z1 : wb;                                               \
    fw[2] = hi ? wc_ : z0;                                              \
    fw[3] = hi ? wd : z1;                                               \
    pfv = __builtin_bit_cast(s16x8, fw);                                \
  }
    MAKE_PF(pf0, sA, 0)
    MAKE_PF(pf1, sA, 8)
    MAKE_PF(pf2, sB, 0)
    MAKE_PF(pf3, sB, 8)
#undef MAKE_PF

    // O^T += V^T . P^T : a=VT[row=d][k=key], b=P[row=q][k=key] -> C[d][q]
    __builtin_amdgcn_s_setprio(1);
    {
      const short* Vr = &Vc[l31 * 64];
      s16x8 v0 = *(const s16x8*)&Vr[(((0 + hi) ^ rs)) << 3];
      o0 = MFMA32(v0, pf0, o0);
      s16x8 v1 = *(const s16x8*)&Vr[(((2 + hi) ^ rs)) << 3];
      o0 = MFMA32(v1, pf1, o0);
      s16x8 v2 = *(const s16x8*)&Vr[(((4 + hi) ^ rs)) << 3];
      o0 = MFMA32(v2, pf2, o0);
      s16x8 v3 = *(const s16x8*)&Vr[(((6 + hi) ^ rs)) << 3];
      o0 = MFMA32(v3, pf3, o0);
      const short* Vr1 = &Vc[(32 + l31) * 64];
      s16x8 w0 = *(const s16x8*)&Vr1[(((0 + hi) ^ rs)) << 3];
      o1 = MFMA32(w0, pf0, o1);
      s16x8 w1 = *(const s16x8*)&Vr1[(((2 + hi) ^ rs)) << 3];
      o1 = MFMA32(w1, pf1, o1);
      s16x8 w2 = *(const s16x8*)&Vr1[(((4 + hi) ^ rs)) << 3];
      o1 = MFMA32(w2, pf2, o1);
      s16x8 w3 = *(const s16x8*)&Vr1[(((6 + hi) ^ rs)) << 3];
      o1 = MFMA32(w3, pf3, o1);
    }
    __builtin_amdgcn_s_setprio(0);

    if (t < 63) {
      const int nb = cur ^ 1;
      *(s16x8*)&smem[nb * 4096 + sd0] = kr0;
      *(s16x8*)&smem[nb * 4096 + sd1] = kr1;
      *(s16x8*)&smem[8192 + nb * 4096 + sd0] = vr0;
      *(s16x8*)&smem[8192 + nb * 4096 + sd1] = vr1;
      __syncthreads();
      cur = nb;
    }
  }

  // Epilogue: O^T (regs=d, col=q) -> LDS [32 q][72] -> coalesced global
  __syncthreads();  // staging LDS reuse
  short* Ow = smem + wid * (32 * 72);
  const float inv = 1.0f / l;
#pragma unroll
  for (int r = 0; r < 16; ++r) {
    const int dd = (r & 3) + 8 * (r >> 2) + 4 * hi;
    Ow[l31 * 72 + dd] = f2bf(o0[r] * inv);
    Ow[l31 * 72 + 32 + dd] = f2bf(o1[r] * inv);
  }
  const int b = bh / 12, h = bh - b * 12;
  const int qq = lane >> 1, c0 = (lane & 1) * 32;
  const size_t gb = ((size_t)(b * 4096 + qbase + qq)) * 768 + h * 64 + c0;
#pragma unroll
  for (int i = 0; i < 4; ++i) {
    s16x8 v = *(const s16x8*)&Ow[qq * 72 + c0 + i * 8];
    *(s16x8*)&Aout[gb + i * 8] = v;
  }
}

// ---------------------------------------------------------------------------
// out = attn @ W_proj + b_proj  (A bf16, W fp32->bf16, out fp32)
// ---------------------------------------------------------------------------
__global__ __launch_bounds__(256) void proj_gemm(
    const unsigned short* __restrict__ A, const float* __restrict__ W,
    const float* __restrict__ bias, float* __restrict__ out) {
  __shared__ short As[BM * LDA];
  __shared__ short Bs[BN * LDA];
  const int K = 768, Nc = 768;
  const int m0 = blockIdx.x * BM, n0 = blockIdx.y * BN;
  const int tid = threadIdx.x, lane = tid & 63, wid = tid >> 6;
  const int wr = wid >> 1, wc = wid & 1;
  const int lr = lane & 15, lk = (lane >> 4) * 8;
  const int sr = tid & 127, sc = (tid >> 7) * 16;

  f32x4 acc[4][4];
#pragma unroll
  for (int i = 0; i < 4; ++i)
#pragma unroll
    for (int j = 0; j < 4; ++j)
#pragma unroll
      for (int e = 0; e < 4; ++e) acc[i][j][e] = 0.f;

  for (int k0 = 0; k0 < K; k0 += BK) {
    {
      const unsigned short* src = A + (size_t)(m0 + sr) * K + k0 + sc;
      *(s16x8*)&As[sr * LDA + sc] = *(const s16x8*)src;
      *(s16x8*)&As[sr * LDA + sc + 8] = *(const s16x8*)(src + 8);
    }
    {
      const float* src = W + (size_t)(k0 + sc) * Nc + n0 + sr;
      s16x8 p0, p1;
#pragma unroll
      for (int i = 0; i < 8; ++i) p0[i] = f2bf(src[(size_t)i * Nc]);
#pragma unroll
      for (int i = 0; i < 8; ++i) p1[i] = f2bf(src[(size_t)(8 + i) * Nc]);
      *(s16x8*)&Bs[sr * LDA + sc] = p0;
      *(s16x8*)&Bs[sr * LDA + sc + 8] = p1;
    }
    __syncthreads();
    s16x8 af[4], bfr[4];
#pragma unroll
    for (int mi = 0; mi < 4; ++mi)
      af[mi] = *(const s16x8*)&As[(wr * 64 + mi * 16 + lr) * LDA + lk];
#pragma unroll
    for (int ni = 0; ni < 4; ++ni)
      bfr[ni] = *(const s16x8*)&Bs[(wc * 64 + ni * 16 + lr) * LDA + lk];
#pragma unroll
    for (int mi = 0; mi < 4; ++mi)
#pragma unroll
      for (int ni = 0; ni < 4; ++ni)
        acc[mi][ni] = MFMA16(af[mi], bfr[ni], acc[mi][ni]);
    __syncthreads();
  }

  const int rbase = m0 + wr * 64 + (lane >> 4) * 4;
#pragma unroll
  for (int ni = 0; ni < 4; ++ni) {
    const int cb = n0 + wc * 64 + ni * 16;
    const float bi = bias[cb + lr];
#pragma unroll
    for (int mi = 0; mi < 4; ++mi) {
#pragma unroll
      for (int j = 0; j < 4; ++j) {
        const int row = rbase + mi * 16 + j;
        out[(size_t)row * 768 + cb + lr] = acc[mi][ni][j] + bi;
      }
    }
  }
}

extern "C" void kernel_launch(void* const* d_in, const int* in_sizes, int n_in,
                              void* d_out, int out_size, void* d_ws, size_t ws_size,
                              hipStream_t stream) {
  const float* x = (const float*)d_in[0];
  const float* W_qkv = (const float*)d_in[1];
  const float* b_qkv = (const float*)d_in[2];
  const float* W_proj = (const float*)d_in[3];
  const float* b_proj = (const float*)d_in[4];
  float* out = (float*)d_out;

  unsigned short* ws = (unsigned short*)d_ws;
  const size_t NQ = (size_t)24 * 4096 * 64;
  unsigned short* q = ws;            // [24][4096][64]
  unsigned short* k = ws + NQ;       // [24][4096][64]
  unsigned short* vt = ws + 2 * NQ;  // [24][64][4096]
  unsigned short* attn = ws + 3 * NQ;

  qkv_gemm<<<dim3(64, 18), 256, 0, stream>>>(x, W_qkv, b_qkv, q, k, vt);
  attn_fwd<<<dim3(32, 24), 256, 0, stream>>>(q, k, vt, attn);
  proj_gemm<<<dim3(64, 6), 256, 0, stream>>>(attn, W_proj, b_proj, out);
}

// Round 4
// 296.728 us; speedup vs baseline: 1.5397x; 1.2440x over previous
//
#include <hip/hip_runtime.h>
#include <hip/hip_bf16.h>

typedef __attribute__((ext_vector_type(4))) float f32x4;
typedef __attribute__((ext_vector_type(16))) float f32x16;
typedef __attribute__((ext_vector_type(8))) short s16x8;
typedef __attribute__((ext_vector_type(4))) unsigned int u32x4;

#define MFMA16(a, b, c) __builtin_amdgcn_mfma_f32_16x16x32_bf16(a, b, c, 0, 0, 0)
#define MFMA32(a, b, c) __builtin_amdgcn_mfma_f32_32x32x16_bf16(a, b, c, 0, 0, 0)

__device__ __forceinline__ short f2bf(float f) {
  unsigned u = __builtin_bit_cast(unsigned, f);
  u += 0x7fffu + ((u >> 16) & 1u);
  return (short)(u >> 16);
}
// packed fp32x2 -> bf16x2 (single HW instruction, RNE)
__device__ __forceinline__ unsigned cvtpk(float lo, float hi) {
  unsigned r;
  asm("v_cvt_pk_bf16_f32 %0, %1, %2" : "=v"(r) : "v"(lo), "v"(hi));
  return r;
}
// raw 2^x
__device__ __forceinline__ float ex2(float x) {
  float r;
  asm("v_exp_f32 %0, %1" : "=v"(r) : "v"(x));
  return r;
}

// ---------------------------------------------------------------------------
// GEMM tiles: 128x128, BK=32, 4 waves (2x2), each wave 64x64 = 4x4 frags.
// ---------------------------------------------------------------------------
#define BM 128
#define BN 128
#define BK 32
#define LDA 40

__global__ __launch_bounds__(256) void qkv_gemm(
    const float* __restrict__ X, const float* __restrict__ W,
    const float* __restrict__ bias, unsigned short* __restrict__ Qo,
    unsigned short* __restrict__ Ko, unsigned short* __restrict__ VTo) {
  __shared__ short As[BM * LDA];
  __shared__ short Bs[BN * LDA];
  const int K = 768, Nc = 2304;
  const int m0 = blockIdx.x * BM, n0 = blockIdx.y * BN;
  const int tid = threadIdx.x, lane = tid & 63, wid = tid >> 6;
  const int wr = wid >> 1, wc = wid & 1;
  const int lr = lane & 15, lk = (lane >> 4) * 8;
  const int sr = tid & 127, sc = (tid >> 7) * 16;

  f32x4 acc[4][4];
#pragma unroll
  for (int i = 0; i < 4; ++i)
#pragma unroll
    for (int j = 0; j < 4; ++j)
#pragma unroll
      for (int e = 0; e < 4; ++e) acc[i][j][e] = 0.f;

  for (int k0 = 0; k0 < K; k0 += BK) {
    {
      const float* src = X + (size_t)(m0 + sr) * K + k0 + sc;
      s16x8 p0, p1;
#pragma unroll
      for (int i = 0; i < 4; ++i) {
        f32x4 f0 = *(const f32x4*)(src + i * 4);
#pragma unroll
        for (int e = 0; e < 4; ++e) {
          if (i < 2) p0[i * 4 + e] = f2bf(f0[e]);
          else       p1[(i - 2) * 4 + e] = f2bf(f0[e]);
        }
      }
      *(s16x8*)&As[sr * LDA + sc] = p0;
      *(s16x8*)&As[sr * LDA + sc + 8] = p1;
    }
    {
      const float* src = W + (size_t)(k0 + sc) * Nc + n0 + sr;
      s16x8 p0, p1;
#pragma unroll
      for (int i = 0; i < 8; ++i) p0[i] = f2bf(src[(size_t)i * Nc]);
#pragma unroll
      for (int i = 0; i < 8; ++i) p1[i] = f2bf(src[(size_t)(8 + i) * Nc]);
      *(s16x8*)&Bs[sr * LDA + sc] = p0;
      *(s16x8*)&Bs[sr * LDA + sc + 8] = p1;
    }
    __syncthreads();
    s16x8 af[4], bfr[4];
#pragma unroll
    for (int mi = 0; mi < 4; ++mi)
      af[mi] = *(const s16x8*)&As[(wr * 64 + mi * 16 + lr) * LDA + lk];
#pragma unroll
    for (int ni = 0; ni < 4; ++ni)
      bfr[ni] = *(const s16x8*)&Bs[(wc * 64 + ni * 16 + lr) * LDA + lk];
#pragma unroll
    for (int mi = 0; mi < 4; ++mi)
#pragma unroll
      for (int ni = 0; ni < 4; ++ni)
        acc[mi][ni] = MFMA16(af[mi], bfr[ni], acc[mi][ni]);
    __syncthreads();
  }

  const float QSC = 0.18033688011f;  // 0.125 * log2(e)
  const int rbase = m0 + wr * 64 + (lane >> 4) * 4;
#pragma unroll
  for (int ni = 0; ni < 4; ++ni) {
    const int cb = n0 + wc * 64 + ni * 16;
    const int which = cb / 768;
    const int rem = cb - which * 768;
    const int h = rem >> 6;
    const int d = (rem & 63) + lr;
    const float bi = bias[cb + lr];
#pragma unroll
    for (int mi = 0; mi < 4; ++mi) {
#pragma unroll
      for (int j = 0; j < 4; ++j) {
        const int row = rbase + mi * 16 + j;
        const int bb = row >> 12, t = row & 4095;
        const float v = acc[mi][ni][j] + bi;
        const size_t hb = (size_t)(bb * 12 + h);
        if (which == 0)
          Qo[(hb * 4096 + t) * 64 + d] = (unsigned short)f2bf(v * QSC);
        else if (which == 1)
          Ko[(hb * 4096 + t) * 64 + d] = (unsigned short)f2bf(v);
        else
          VTo[(hb * 64 + d) * 4096 + t] = (unsigned short)f2bf(v);
      }
    }
  }
}

// ---------------------------------------------------------------------------
// Flash attention, swapped-QK^T 32x32 structure:
// 4 warps x 32 q-rows, KVBLK=64, mfma_f32_32x32x16_bf16.
// LDS swizzle: 16B slot ^= SW(row), SW(r) = (r + r>>3) & 7 — spreads rows
// congruent mod 8 across distinct bank-quads (128B rows wrap all 32 banks).
// ---------------------------------------------------------------------------
__global__ __launch_bounds__(256) void attn_fwd(
    const unsigned short* __restrict__ Qg, const unsigned short* __restrict__ Kg,
    const unsigned short* __restrict__ VTg, unsigned short* __restrict__ Aout) {
  __shared__ __align__(16) short smem[16384];  // [K0|K1|V0|V1] 4096 each
  const int qt = blockIdx.x, bh = blockIdx.y;
  const unsigned short* Qh = Qg + (size_t)bh * 4096 * 64;
  const unsigned short* Kh = Kg + (size_t)bh * 4096 * 64;
  const unsigned short* Vh = VTg + (size_t)bh * 4096 * 64;  // [d][tok]
  const int tid = threadIdx.x, lane = tid & 63, wid = tid >> 6;
  const int l31 = lane & 31, hi = lane >> 5;
  const int sw0 = (l31 + (l31 >> 3)) & 7;   // SW(l31)
  const int sw1 = (sw0 + 4) & 7;            // SW(32+l31)
  const int qbase = qt * 128 + wid * 32;

  // Q as B-fragments: row=q=l31, k = db*16 + hi*8 + i
  s16x8 qf[4];
#pragma unroll
  for (int db = 0; db < 4; ++db)
    qf[db] = *(const s16x8*)&Qh[(size_t)(qbase + l31) * 64 + db * 16 + hi * 8];

  f32x16 zf;
#pragma unroll
  for (int r = 0; r < 16; ++r) zf[r] = 0.f;
  f32x16 o0 = zf, o1 = zf;  // O^T: col=q=l31, regs=d
  float m = -1e30f, l = 0.f;

  // staging: 256 threads x 32B per tile per matrix
  const int srow = tid >> 2, sp = tid & 3;
  const int ssw = (srow + (srow >> 3)) & 7;
  const int sd0 = srow * 64 + (((sp * 2) ^ ssw) << 3);
  const int sd1 = srow * 64 + (((sp * 2 + 1) ^ ssw) << 3);
  const unsigned short* kga = Kh + srow * 64 + sp * 16;
  const unsigned short* vga = Vh + (size_t)srow * 4096 + sp * 16;

  s16x8 kr0 = *(const s16x8*)kga;
  s16x8 kr1 = *(const s16x8*)(kga + 8);
  s16x8 vr0 = *(const s16x8*)vga;
  s16x8 vr1 = *(const s16x8*)(vga + 8);
  *(s16x8*)&smem[sd0] = kr0;
  *(s16x8*)&smem[sd1] = kr1;
  *(s16x8*)&smem[8192 + sd0] = vr0;
  *(s16x8*)&smem[8192 + sd1] = vr1;
  __syncthreads();

  int cur = 0;
  for (int t = 0; t < 64; ++t) {
    if (t < 63) {
      kr0 = *(const s16x8*)(kga + (size_t)(t + 1) * 4096);
      kr1 = *(const s16x8*)(kga + (size_t)(t + 1) * 4096 + 8);
      vr0 = *(const s16x8*)(vga + (t + 1) * 64);
      vr1 = *(const s16x8*)(vga + (t + 1) * 64 + 8);
    }
    const short* Kc = smem + cur * 4096;
    const short* Vc = smem + 8192 + cur * 4096;

    // S^T = K . Q^T : C[key][q] (col=q=l31)
    f32x16 sA = zf, sB = zf;
    __builtin_amdgcn_s_setprio(1);
#pragma unroll
    for (int db = 0; db < 4; ++db) {
      s16x8 kf = *(const s16x8*)&Kc[l31 * 64 + (((db * 2 + hi) ^ sw0) << 3)];
      sA = MFMA32(kf, qf[db], sA);
    }
#pragma unroll
    for (int db = 0; db < 4; ++db) {
      s16x8 kf = *(const s16x8*)&Kc[(32 + l31) * 64 + (((db * 2 + hi) ^ sw1) << 3)];
      sB = MFMA32(kf, qf[db], sB);
    }
    __builtin_amdgcn_s_setprio(0);

    // lane-local softmax for q=l31 (keys: 32 local + 32 on lane^32)
    float mx[16];
#pragma unroll
    for (int r = 0; r < 16; ++r) mx[r] = fmaxf(sA[r], sB[r]);
#pragma unroll
    for (int off = 8; off; off >>= 1)
#pragma unroll
      for (int r = 0; r < off; ++r) mx[r] = fmaxf(mx[r], mx[r + off]);
    const float pmax = fmaxf(mx[0], __shfl_xor(mx[0], 32));

    if (!__all(pmax <= m + 8.0f)) {  // defer-max (T13)
      const float mnew = fmaxf(m, pmax);
      const float scl = ex2(m - mnew);
#pragma unroll
      for (int r = 0; r < 16; ++r) { o0[r] *= scl; o1[r] *= scl; }
      l *= scl;
      m = mnew;
    }
#pragma unroll
    for (int r = 0; r < 16; ++r) {
      sA[r] = ex2(sA[r] - m);
      sB[r] = ex2(sB[r] - m);
    }
    float t8[8];
#pragma unroll
    for (int r = 0; r < 8; ++r)
      t8[r] = (sA[r] + sA[r + 8]) + (sB[r] + sB[r + 8]);
#pragma unroll
    for (int off = 4; off; off >>= 1)
#pragma unroll
      for (int r = 0; r < off; ++r) t8[r] += t8[r + off];
    l += t8[0] + __shfl_xor(t8[0], 32);

    // Build PV B-fragments in-register: pf[kc] = P[q=l31][kc*16+hi*8+0..7]
    s16x8 pf0, pf1, pf2, pf3;
#define MAKE_PF(pfv, sv, base)                                          \
  {                                                                     \
    unsigned wa = cvtpk(sv[base + 0], sv[base + 1]);                    \
    unsigned wb = cvtpk(sv[base + 2], sv[base + 3]);                    \
    unsigned wc_ = cvtpk(sv[base + 4], sv[base + 5]);                   \
    unsigned wd = cvtpk(sv[base + 6], sv[base + 7]);                    \
    unsigned z0 = (unsigned)__shfl_xor((int)(hi ? wa : wc_), 32);       \
    unsigned z1 = (unsigned)__shfl_xor((int)(hi ? wb : wd), 32);        \
    u32x4 fw;                                                           \
    fw[0] = hi ? z0 : wa;                                               \
    fw[1] = hi ? z1 : wb;                                               \
    fw[2] = hi ? wc_ : z0;                                              \
    fw[3] = hi ? wd : z1;                                               \
    pfv = __builtin_bit_cast(s16x8, fw);                                \
  }
    MAKE_PF(pf0, sA, 0)
    MAKE_PF(pf1, sA, 8)
    MAKE_PF(pf2, sB, 0)
    MAKE_PF(pf3, sB, 8)
#undef MAKE_PF

    // O^T += V^T . P^T : a=VT[row=d][k=key], b=P[row=q][k=key] -> C[d][q]
    __builtin_amdgcn_s_setprio(1);
    {
      const short* Vr = &Vc[l31 * 64];
      s16x8 v0 = *(const s16x8*)&Vr[((0 + hi) ^ sw0) << 3];
      o0 = MFMA32(v0, pf0, o0);
      s16x8 v1 = *(const s16x8*)&Vr[((2 + hi) ^ sw0) << 3];
      o0 = MFMA32(v1, pf1, o0);
      s16x8 v2 = *(const s16x8*)&Vr[((4 + hi) ^ sw0) << 3];
      o0 = MFMA32(v2, pf2, o0);
      s16x8 v3 = *(const s16x8*)&Vr[((6 + hi) ^ sw0) << 3];
      o0 = MFMA32(v3, pf3, o0);
      const short* Vr1 = &Vc[(32 + l31) * 64];
      s16x8 w0 = *(const s16x8*)&Vr1[((0 + hi) ^ sw1) << 3];
      o1 = MFMA32(w0, pf0, o1);
      s16x8 w1 = *(const s16x8*)&Vr1[((2 + hi) ^ sw1) << 3];
      o1 = MFMA32(w1, pf1, o1);
      s16x8 w2 = *(const s16x8*)&Vr1[((4 + hi) ^ sw1) << 3];
      o1 = MFMA32(w2, pf2, o1);
      s16x8 w3 = *(const s16x8*)&Vr1[((6 + hi) ^ sw1) << 3];
      o1 = MFMA32(w3, pf3, o1);
    }
    __builtin_amdgcn_s_setprio(0);

    if (t < 63) {
      const int nb = cur ^ 1;
      *(s16x8*)&smem[nb * 4096 + sd0] = kr0;
      *(s16x8*)&smem[nb * 4096 + sd1] = kr1;
      *(s16x8*)&smem[8192 + nb * 4096 + sd0] = vr0;
      *(s16x8*)&smem[8192 + nb * 4096 + sd1] = vr1;
      __syncthreads();
      cur = nb;
    }
  }

  // Epilogue: O^T (regs=d, col=q) -> LDS [32 q][72] -> coalesced global
  __syncthreads();  // staging LDS reuse
  short* Ow = smem + wid * (32 * 72);
  const float inv = 1.0f / l;
#pragma unroll
  for (int r = 0; r < 16; ++r) {
    const int dd = (r & 3) + 8 * (r >> 2) + 4 * hi;
    Ow[l31 * 72 + dd] = f2bf(o0[r] * inv);
    Ow[l31 * 72 + 32 + dd] = f2bf(o1[r] * inv);
  }
  const int b = bh / 12, h = bh - b * 12;
  const int qq = lane >> 1, c0 = (lane & 1) * 32;
  const size_t gb = ((size_t)(b * 4096 + qbase + qq)) * 768 + h * 64 + c0;
#pragma unroll
  for (int i = 0; i < 4; ++i) {
    s16x8 v = *(const s16x8*)&Ow[qq * 72 + c0 + i * 8];
    *(s16x8*)&Aout[gb + i * 8] = v;
  }
}

// ---------------------------------------------------------------------------
// out = attn @ W_proj + b_proj  (A bf16, W fp32->bf16, out fp32)
// ---------------------------------------------------------------------------
__global__ __launch_bounds__(256) void proj_gemm(
    const unsigned short* __restrict__ A, const float* __restrict__ W,
    const float* __restrict__ bias, float* __restrict__ out) {
  __shared__ short As[BM * LDA];
  __shared__ short Bs[BN * LDA];
  const int K = 768, Nc = 768;
  const int m0 = blockIdx.x * BM, n0 = blockIdx.y * BN;
  const int tid = threadIdx.x, lane = tid & 63, wid = tid >> 6;
  const int wr = wid >> 1, wc = wid & 1;
  const int lr = lane & 15, lk = (lane >> 4) * 8;
  const int sr = tid & 127, sc = (tid >> 7) * 16;

  f32x4 acc[4][4];
#pragma unroll
  for (int i = 0; i < 4; ++i)
#pragma unroll
    for (int j = 0; j < 4; ++j)
#pragma unroll
      for (int e = 0; e < 4; ++e) acc[i][j][e] = 0.f;

  for (int k0 = 0; k0 < K; k0 += BK) {
    {
      const unsigned short* src = A + (size_t)(m0 + sr) * K + k0 + sc;
      *(s16x8*)&As[sr * LDA + sc] = *(const s16x8*)src;
      *(s16x8*)&As[sr * LDA + sc + 8] = *(const s16x8*)(src + 8);
    }
    {
      const float* src = W + (size_t)(k0 + sc) * Nc + n0 + sr;
      s16x8 p0, p1;
#pragma unroll
      for (int i = 0; i < 8; ++i) p0[i] = f2bf(src[(size_t)i * Nc]);
#pragma unroll
      for (int i = 0; i < 8; ++i) p1[i] = f2bf(src[(size_t)(8 + i) * Nc]);
      *(s16x8*)&Bs[sr * LDA + sc] = p0;
      *(s16x8*)&Bs[sr * LDA + sc + 8] = p1;
    }
    __syncthreads();
    s16x8 af[4], bfr[4];
#pragma unroll
    for (int mi = 0; mi < 4; ++mi)
      af[mi] = *(const s16x8*)&As[(wr * 64 + mi * 16 + lr) * LDA + lk];
#pragma unroll
    for (int ni = 0; ni < 4; ++ni)
      bfr[ni] = *(const s16x8*)&Bs[(wc * 64 + ni * 16 + lr) * LDA + lk];
#pragma unroll
    for (int mi = 0; mi < 4; ++mi)
#pragma unroll
      for (int ni = 0; ni < 4; ++ni)
        acc[mi][ni] = MFMA16(af[mi], bfr[ni], acc[mi][ni]);
    __syncthreads();
  }

  const int rbase = m0 + wr * 64 + (lane >> 4) * 4;
#pragma unroll
  for (int ni = 0; ni < 4; ++ni) {
    const int cb = n0 + wc * 64 + ni * 16;
    const float bi = bias[cb + lr];
#pragma unroll
    for (int mi = 0; mi < 4; ++mi) {
#pragma unroll
      for (int j = 0; j < 4; ++j) {
        const int row = rbase + mi * 16 + j;
        out[(size_t)row * 768 + cb + lr] = acc[mi][ni][j] + bi;
      }
    }
  }
}

extern "C" void kernel_launch(void* const* d_in, const int* in_sizes, int n_in,
                              void* d_out, int out_size, void* d_ws, size_t ws_size,
                              hipStream_t stream) {
  const float* x = (const float*)d_in[0];
  const float* W_qkv = (const float*)d_in[1];
  const float* b_qkv = (const float*)d_in[2];
  const float* W_proj = (const float*)d_in[3];
  const float* b_proj = (const float*)d_in[4];
  float* out = (float*)d_out;

  unsigned short* ws = (unsigned short*)d_ws;
  const size_t NQ = (size_t)24 * 4096 * 64;
  unsigned short* q = ws;            // [24][4096][64]
  unsigned short* k = ws + NQ;       // [24][4096][64]
  unsigned short* vt = ws + 2 * NQ;  // [24][64][4096]
  unsigned short* attn = ws + 3 * NQ;

  qkv_gemm<<<dim3(64, 18), 256, 0, stream>>>(x, W_qkv, b_qkv, q, k, vt);
  attn_fwd<<<dim3(32, 24), 256, 0, stream>>>(q, k, vt, attn);
  proj_gemm<<<dim3(64, 6), 256, 0, stream>>>(attn, W_proj, b_proj, out);
}